// Round 3
// baseline (111.341 us; speedup 1.0000x reference)
//
#include <hip/hip_runtime.h>

// ---------------------------------------------------------------------------
// SpeciesSpecificNetworkBranch — bf16 MFMA, BN folded into weights, pre-packed
// A-frags, software-pipelined gathers.
//
// math: z1 = W1^T x + b1
//       z2 = W2f^T relu(z1) + Wsc^T x + bias2f     (W2f = diag(A1) W2,
//            bias2f = C1@W2 + b2 + bsc)            (A1,C1 = BN1 eval affine)
//       out = relu(Wshf_s^T relu(z2) + bshf_s)*.92 (Wshf_s = diag(A2_s) Wsh,
//            bshf_s = C2_s@Wsh + bsh)
// Each wave owns a 128-row single-species chunk (4 tiles of 32). Per layer the
// transposed activations C'[feature][sample] come from mfma_f32_32x32x16_bf16
// (A = W^T frags held in regs, B = activations); sample stays lane-local so
// relu + v_cvt_pk_bf16_f32 + permlane32_swap chains layers entirely in regs.
// ---------------------------------------------------------------------------

#define EPSBN 1e-5f
#define NBP 1024
#define TPB 256
#define SEG 128          // rows per wave-chunk (4 tiles x 32)
#define NPRE 42          // extra blocks in k_count doing weight pre-pack

// ws int-offsets:
//   0..4    cnt[5]
//   8..13   po[6]
//   16..20  cur[5]
//   32..511        bconst floats [s][q][hi][16]  (q: 0=b1 1=bias2f 2=bshf) 480
//   512..10751     wfrag uints [s][m][c][64][4]  (m: 0=W1 1=Wsc 2=W2f 3=Wshf)
//   10752..        bucket[B + 5*SEG]

typedef __attribute__((ext_vector_type(8))) short bf16x8;
typedef __attribute__((ext_vector_type(16))) float f32x16;
typedef __attribute__((ext_vector_type(4))) unsigned u32x4;

union FU { unsigned u[4]; bf16x8 v; u32x4 q; };

static __device__ __forceinline__ unsigned pkbf(float lo, float hi) {
    unsigned r;
    asm("v_cvt_pk_bf16_f32 %0, %1, %2" : "=v"(r) : "v"(lo), "v"(hi));
    return r;
}

// --- count + (concurrently) pre-pack folded weights into frag layout --------
__global__ void k_count(const int* __restrict__ sid, int B, int* __restrict__ cnt,
                        unsigned* __restrict__ wfrag, float* __restrict__ bconst,
                        const float* __restrict__ W1, const float* __restrict__ b1,
                        const float* __restrict__ g1, const float* __restrict__ be1,
                        const float* __restrict__ mu1, const float* __restrict__ va1,
                        const float* __restrict__ W2, const float* __restrict__ b2,
                        const float* __restrict__ g2, const float* __restrict__ be2,
                        const float* __restrict__ mu2, const float* __restrict__ va2,
                        const float* __restrict__ Wsc, const float* __restrict__ bsc,
                        const float* __restrict__ Wsh, const float* __restrict__ bsh) {
    if (blockIdx.x >= NBP) {
        const int e = blockIdx.x - NBP;
        if (e < 40) {
            const int i = e * 256 + threadIdx.x;   // wfrag word index, 10240 total
            const int p = i & 3, l = (i >> 2) & 63, c = (i >> 8) & 1;
            const int m = (i >> 9) & 3, s = i >> 11;
            const int ln = l & 31, hi = l >> 5;
            const int k0 = c * 16 + hi * 8 + 2 * p;
            float lo, hv;
            if (m == 0)      { lo = W1[s*1024 + k0*32 + ln];  hv = W1[s*1024 + (k0+1)*32 + ln]; }
            else if (m == 1) { lo = Wsc[s*1024 + k0*32 + ln]; hv = Wsc[s*1024 + (k0+1)*32 + ln]; }
            else if (m == 2) {
                float A0 = g1[s*32+k0]   * rsqrtf(va1[s*32+k0]   + EPSBN);
                float A1 = g1[s*32+k0+1] * rsqrtf(va1[s*32+k0+1] + EPSBN);
                lo = A0 * W2[s*1024 + k0*32 + ln]; hv = A1 * W2[s*1024 + (k0+1)*32 + ln];
            } else {
                float A0 = g2[s*32+k0]   * rsqrtf(va2[s*32+k0]   + EPSBN);
                float A1 = g2[s*32+k0+1] * rsqrtf(va2[s*32+k0+1] + EPSBN);
                lo = A0 * Wsh[k0*32 + ln]; hv = A1 * Wsh[(k0+1)*32 + ln];
            }
            wfrag[i] = pkbf(lo, hv);
        } else {
            const int i = (e - 40) * 256 + threadIdx.x;  // bconst index, 480 total
            if (i < 480) {
                const int reg = i & 15, hi = (i >> 4) & 1, t = i >> 5;
                const int q = t % 3, s = t / 3;
                const int r = (reg & 3) + 8 * (reg >> 2) + 4 * hi;
                float v;
                if (q == 0) v = b1[s*32 + r];
                else if (q == 1) {
                    v = b2[s*32 + r] + bsc[s*32 + r];
                    for (int k = 0; k < 32; ++k) {
                        float A = g1[s*32+k] * rsqrtf(va1[s*32+k] + EPSBN);
                        float C = be1[s*32+k] - mu1[s*32+k] * A;
                        v = fmaf(C, W2[s*1024 + k*32 + r], v);
                    }
                } else {
                    v = bsh[r];
                    for (int k = 0; k < 32; ++k) {
                        float A = g2[s*32+k] * rsqrtf(va2[s*32+k] + EPSBN);
                        float C = be2[s*32+k] - mu2[s*32+k] * A;
                        v = fmaf(C, Wsh[k*32 + r], v);
                    }
                }
                bconst[i] = v;
            }
        }
        return;
    }
    __shared__ int lcnt[8];
    if (threadIdx.x < 8) lcnt[threadIdx.x] = 0;
    __syncthreads();
    const int lane = threadIdx.x & 63;
    int c0 = 0, c1 = 0, c2 = 0, c3 = 0, c4 = 0;
    const int stride = NBP * TPB;
    int i = blockIdx.x * TPB + threadIdx.x;
    const int iters = (B + stride - 1) / stride;
    for (int it = 0; it < iters; ++it, i += stride) {
        int s = (i < B) ? sid[i] : -1;
        c0 += (int)__popcll(__ballot(s == 0));
        c1 += (int)__popcll(__ballot(s == 1));
        c2 += (int)__popcll(__ballot(s == 2));
        c3 += (int)__popcll(__ballot(s == 3));
        c4 += (int)__popcll(__ballot(s == 4));
    }
    if (lane == 0) {
        atomicAdd(&lcnt[0], c0); atomicAdd(&lcnt[1], c1);
        atomicAdd(&lcnt[2], c2); atomicAdd(&lcnt[3], c3);
        atomicAdd(&lcnt[4], c4);
    }
    __syncthreads();
    if (threadIdx.x < 5) atomicAdd(&cnt[threadIdx.x], lcnt[threadIdx.x]);
}

__global__ void k_offsets(const int* __restrict__ cnt, int* __restrict__ po,
                          int* __restrict__ cur, int* __restrict__ bucket) {
    __shared__ int spo[6];
    if (threadIdx.x == 0) {
        int o = 0;
        for (int s = 0; s < 5; ++s) {
            spo[s] = o; po[s] = o; cur[s] = o;
            o += (cnt[s] + SEG - 1) & ~(SEG - 1);
        }
        spo[5] = o; po[5] = o;
    }
    __syncthreads();
    for (int s = 0; s < 5; ++s)
        for (int p = spo[s] + cnt[s] + (int)threadIdx.x; p < spo[s + 1]; p += blockDim.x)
            bucket[p] = -1;
}

__global__ void k_scatter(const int* __restrict__ sid, int B, int* __restrict__ cur,
                          int* __restrict__ bucket) {
    __shared__ int wq[8][4][5];
    __shared__ int bbase[5];
    const int lane = threadIdx.x & 63;
    const int wav  = threadIdx.x >> 6;
    const int stride = gridDim.x * blockDim.x;
    const int start  = blockIdx.x * blockDim.x + threadIdx.x;
    const int iters  = (B + stride - 1) / stride;
    for (int it = 0; it < iters; ++it) {
        int i = start + it * stride;
        int s = (i < B) ? sid[i] : -1;
        #pragma unroll
        for (int sp = 0; sp < 5; ++sp) {
            unsigned long long m = __ballot(s == sp);
            if (lane == 0) wq[it][wav][sp] = (int)__popcll(m);
        }
    }
    __syncthreads();
    if (threadIdx.x < 5) {
        int tot = 0;
        for (int t = 0; t < iters; ++t)
            for (int w = 0; w < 4; ++w) tot += wq[t][w][threadIdx.x];
        bbase[threadIdx.x] = atomicAdd(&cur[threadIdx.x], tot);
    }
    __syncthreads();
    for (int it = 0; it < iters; ++it) {
        int i = start + it * stride;
        int s = (i < B) ? sid[i] : -1;
        int rank = 0;
        #pragma unroll
        for (int sp = 0; sp < 5; ++sp) {
            unsigned long long m = __ballot(s == sp);
            if (s == sp) rank = (int)__popcll(m & ((1ull << lane) - 1ull));
        }
        if (s >= 0) {
            int off = bbase[s];
            for (int t = 0; t < it; ++t)
                #pragma unroll
                for (int w = 0; w < 4; ++w) off += wq[t][w][s];
            for (int w = 0; w < wav; ++w) off += wq[it][w][s];
            bucket[off + rank] = i;
        }
    }
}

// relu-only transition: C' acc -> next layer's B-frags (cvt_pk + permlane32).
static __device__ __forceinline__ void reluT(const f32x16& c, bf16x8& f0, bf16x8& f1) {
    unsigned p[8];
    #pragma unroll
    for (int i = 0; i < 8; ++i)
        p[i] = pkbf(fmaxf(c[2 * i], 0.f), fmaxf(c[2 * i + 1], 0.f));
    auto s0 = __builtin_amdgcn_permlane32_swap(p[0], p[2], false, false);
    auto s1 = __builtin_amdgcn_permlane32_swap(p[1], p[3], false, false);
    auto s2 = __builtin_amdgcn_permlane32_swap(p[4], p[6], false, false);
    auto s3 = __builtin_amdgcn_permlane32_swap(p[5], p[7], false, false);
    FU u0, u1;
    u0.u[0] = s0[0]; u0.u[1] = s1[0]; u0.u[2] = s0[1]; u0.u[3] = s1[1];
    u1.u[0] = s2[0]; u1.u[1] = s3[0]; u1.u[2] = s2[1]; u1.u[3] = s3[1];
    f0 = u0.v; f1 = u1.v;
}

struct XR { float4 a, b, c, d; };

static __device__ __forceinline__ XR ldx(const float* __restrict__ X, long ofs, int hi) {
    const float* xb = X + ofs + hi * 8;
    XR r;
    r.a = *(const float4*)(xb);
    r.b = *(const float4*)(xb + 4);
    r.c = *(const float4*)(xb + 16);
    r.d = *(const float4*)(xb + 20);
    return r;
}

static __device__ __forceinline__ void cvtx(const XR& x, bf16x8& b0, bf16x8& b1) {
    FU u0, u1;
    u0.u[0] = pkbf(x.a.x, x.a.y); u0.u[1] = pkbf(x.a.z, x.a.w);
    u0.u[2] = pkbf(x.b.x, x.b.y); u0.u[3] = pkbf(x.b.z, x.b.w);
    u1.u[0] = pkbf(x.c.x, x.c.y); u1.u[1] = pkbf(x.c.z, x.c.w);
    u1.u[2] = pkbf(x.d.x, x.d.y); u1.u[3] = pkbf(x.d.z, x.d.w);
    b0 = u0.v; b1 = u1.v;
}

static __device__ __forceinline__ void chain_store(
        bf16x8 bx0, bf16x8 bx1, const bf16x8 wf[4][2],
        const f32x16& cb1, const f32x16& cb2, const f32x16& cb3,
        bool valid, float* __restrict__ op) {
    f32x16 a1 = cb1, a2 = cb2;
    a1 = __builtin_amdgcn_mfma_f32_32x32x16_bf16(wf[0][0], bx0, a1, 0, 0, 0);
    a1 = __builtin_amdgcn_mfma_f32_32x32x16_bf16(wf[0][1], bx1, a1, 0, 0, 0);
    a2 = __builtin_amdgcn_mfma_f32_32x32x16_bf16(wf[1][0], bx0, a2, 0, 0, 0);
    a2 = __builtin_amdgcn_mfma_f32_32x32x16_bf16(wf[1][1], bx1, a2, 0, 0, 0);
    bf16x8 h0, h1;
    reluT(a1, h0, h1);
    a2 = __builtin_amdgcn_mfma_f32_32x32x16_bf16(wf[2][0], h0, a2, 0, 0, 0);
    a2 = __builtin_amdgcn_mfma_f32_32x32x16_bf16(wf[2][1], h1, a2, 0, 0, 0);
    bf16x8 g0, g1;
    reluT(a2, g0, g1);
    f32x16 a3 = cb3;
    a3 = __builtin_amdgcn_mfma_f32_32x32x16_bf16(wf[3][0], g0, a3, 0, 0, 0);
    a3 = __builtin_amdgcn_mfma_f32_32x32x16_bf16(wf[3][1], g1, a3, 0, 0, 0);
    if (valid) {
        #pragma unroll
        for (int q = 0; q < 4; ++q) {
            float4 v;
            v.x = fmaxf(a3[4 * q + 0], 0.f) * 0.92f;
            v.y = fmaxf(a3[4 * q + 1], 0.f) * 0.92f;
            v.z = fmaxf(a3[4 * q + 2], 0.f) * 0.92f;
            v.w = fmaxf(a3[4 * q + 3], 0.f) * 0.92f;
            *(float4*)(op + q * 8) = v;
        }
    }
}

__global__ __launch_bounds__(256, 2) void k_main(
    const float* __restrict__ X, const int* __restrict__ bucket,
    const int* __restrict__ po, const unsigned* __restrict__ wfrag,
    const float* __restrict__ bconst, float* __restrict__ out) {
    const int l  = threadIdx.x & 63;
    const int ln = l & 31;
    const int hi = l >> 5;
    const int chunk = (blockIdx.x * blockDim.x + threadIdx.x) >> 6;
    const int base  = chunk * SEG;
    if (base >= po[5]) return;

    // bucket indices for all 4 tiles — issue first, independent of species
    const int i0 = bucket[base + ln];
    const int i1 = bucket[base + 32 + ln];
    const int i2 = bucket[base + 64 + ln];
    const int i3 = bucket[base + 96 + ln];

    int s = 0;
    #pragma unroll
    for (int t = 1; t < 5; ++t) s += (base >= po[t]) ? 1 : 0;
    s = __builtin_amdgcn_readfirstlane(s);

    // weights: 8 coalesced dwordx4 from pre-packed frag table
    bf16x8 wf[4][2];
    #pragma unroll
    for (int m = 0; m < 4; ++m)
        #pragma unroll
        for (int c = 0; c < 2; ++c) {
            FU u;
            u.q = *(const u32x4*)(wfrag + (((s * 4 + m) * 2 + c) * 64 + l) * 4);
            wf[m][c] = u.v;
        }

    // consts: 3 x f32x16 (values depend only on (hi,reg) — same 64B per half-wave)
    const f32x16 cb1 = *(const f32x16*)(bconst + ((s * 3 + 0) * 2 + hi) * 16);
    const f32x16 cb2 = *(const f32x16*)(bconst + ((s * 3 + 1) * 2 + hi) * 16);
    const f32x16 cb3 = *(const f32x16*)(bconst + ((s * 3 + 2) * 2 + hi) * 16);

    const long o0 = (i0 >= 0) ? (long)i0 * 32 : 0;
    const long o1 = (i1 >= 0) ? (long)i1 * 32 : 0;
    const long o2 = (i2 >= 0) ? (long)i2 * 32 : 0;
    const long o3 = (i3 >= 0) ? (long)i3 * 32 : 0;

    // software pipeline: two X buffers, reload each the moment it's converted
    XR xA = ldx(X, o0, hi);
    XR xB = ldx(X, o1, hi);
    bf16x8 p0, p1, q0, q1;

    cvtx(xA, p0, p1);
    xA = ldx(X, o2, hi);
    chain_store(p0, p1, wf, cb1, cb2, cb3, i0 >= 0, out + o0 + hi * 4);

    cvtx(xB, q0, q1);
    xB = ldx(X, o3, hi);
    chain_store(q0, q1, wf, cb1, cb2, cb3, i1 >= 0, out + o1 + hi * 4);

    cvtx(xA, p0, p1);
    chain_store(p0, p1, wf, cb1, cb2, cb3, i2 >= 0, out + o2 + hi * 4);

    cvtx(xB, q0, q1);
    chain_store(q0, q1, wf, cb1, cb2, cb3, i3 >= 0, out + o3 + hi * 4);
}

extern "C" void kernel_launch(void* const* d_in, const int* in_sizes, int n_in,
                              void* d_out, int out_size, void* d_ws, size_t ws_size,
                              hipStream_t stream) {
    const float* X   = (const float*)d_in[0];
    const int*   sid = (const int*)d_in[1];
    const float* W1  = (const float*)d_in[2];
    const float* b1  = (const float*)d_in[3];
    const float* g1  = (const float*)d_in[4];
    const float* be1 = (const float*)d_in[5];
    const float* mu1 = (const float*)d_in[6];
    const float* va1 = (const float*)d_in[7];
    const float* W2  = (const float*)d_in[8];
    const float* b2  = (const float*)d_in[9];
    const float* g2  = (const float*)d_in[10];
    const float* be2 = (const float*)d_in[11];
    const float* mu2 = (const float*)d_in[12];
    const float* va2 = (const float*)d_in[13];
    const float* Wsc = (const float*)d_in[14];
    const float* bsc = (const float*)d_in[15];
    const float* Wsh = (const float*)d_in[16];
    const float* bsh = (const float*)d_in[17];
    float* out = (float*)d_out;
    const int B = in_sizes[1];

    int* ws        = (int*)d_ws;
    int* cnt       = ws;
    int* po        = ws + 8;
    int* cur       = ws + 16;
    float* bconst  = (float*)(ws + 32);
    unsigned* wfrag = (unsigned*)(ws + 512);
    int* bucket    = ws + 10752;

    hipMemsetAsync(cnt, 0, 24 * sizeof(int), stream);
    k_count<<<NBP + NPRE, TPB, 0, stream>>>(sid, B, cnt, wfrag, bconst,
                                            W1, b1, g1, be1, mu1, va1,
                                            W2, b2, g2, be2, mu2, va2,
                                            Wsc, bsc, Wsh, bsh);
    k_offsets<<<1, TPB, 0, stream>>>(cnt, po, cur, bucket);
    k_scatter<<<NBP, TPB, 0, stream>>>(sid, B, cur, bucket);

    const int nchunks = (B + 5 * (SEG - 1) + SEG - 1) / SEG;
    const int nblocks = (nchunks + 3) / 4;   // 4 waves (= 4 chunks) per block
    k_main<<<nblocks, TPB, 0, stream>>>(X, bucket, po, wfrag, bconst, out);
}

// Round 4
// 80.873 us; speedup vs baseline: 1.3767x; 1.3767x over previous
//
#include <hip/hip_runtime.h>

// ---------------------------------------------------------------------------
// SpeciesSpecificNetworkBranch — dense bf16 MFMA version (no gather/scatter).
//
// R3 post-mortem: bucketing made X reads random 32-64B gathers and out writes
// random scatters -> ~2 TB/s effective HBM -> 90us. Here rows stay in natural
// order (pure streaming); each 32-row tile computes ALL 5 species' chains
// (5x MFMA is only ~4us/CU) and per-lane selects by species id. Weights/biases
// are BN-folded and frag-packed by a tiny pre-kernel, staged to LDS per block.
//
// math: z1 = W1^T x + b1
//       z2 = W2f^T relu(z1) + Wsc^T x + bias2f     (W2f = diag(A1) W2)
//       out = relu(Wshf_s^T relu(z2) + bshf_s)*.92 (Wshf_s = diag(A2_s) Wsh)
// C'[feature][sample] from mfma_f32_32x32x16_bf16; sample lane-local, so
// relu + v_cvt_pk_bf16_f32 + permlane32_swap chains layers in registers.
// ---------------------------------------------------------------------------

#define EPSBN 1e-5f
#define TPB 256
#define NBLK 768   // 3 blocks/CU on 256 CUs

typedef __attribute__((ext_vector_type(8))) short bf16x8;
typedef __attribute__((ext_vector_type(16))) float f32x16;
typedef __attribute__((ext_vector_type(4))) unsigned u32x4;

union FU { unsigned u[4]; bf16x8 v; u32x4 q; };

static __device__ __forceinline__ unsigned pkbf(float lo, float hi) {
    unsigned r;
    asm("v_cvt_pk_bf16_f32 %0, %1, %2" : "=v"(r) : "v"(lo), "v"(hi));
    return r;
}

// --- pre-pack: fold BN into weights/biases, pack MFMA A-frags --------------
// wfrag uints [s][m][c][64][4]  (m: 0=W1 1=Wsc 2=W2f 3=Wshf), 10240 words
// bconst floats [s][q][hi][16]  (q: 0=b1 1=bias2f 2=bshf), 480 floats
__global__ void k_pre(unsigned* __restrict__ wfrag, float* __restrict__ bconst,
                      const float* __restrict__ W1, const float* __restrict__ b1,
                      const float* __restrict__ g1, const float* __restrict__ be1,
                      const float* __restrict__ mu1, const float* __restrict__ va1,
                      const float* __restrict__ W2, const float* __restrict__ b2,
                      const float* __restrict__ g2, const float* __restrict__ be2,
                      const float* __restrict__ mu2, const float* __restrict__ va2,
                      const float* __restrict__ Wsc, const float* __restrict__ bsc,
                      const float* __restrict__ Wsh, const float* __restrict__ bsh) {
    if (blockIdx.x < 40) {
        const int i = blockIdx.x * 256 + threadIdx.x;   // wfrag word index
        const int p = i & 3, l = (i >> 2) & 63, c = (i >> 8) & 1;
        const int m = (i >> 9) & 3, s = i >> 11;
        const int ln = l & 31, hi = l >> 5;
        const int k0 = c * 16 + hi * 8 + 2 * p;
        float lo, hv;
        if (m == 0)      { lo = W1[s*1024 + k0*32 + ln];  hv = W1[s*1024 + (k0+1)*32 + ln]; }
        else if (m == 1) { lo = Wsc[s*1024 + k0*32 + ln]; hv = Wsc[s*1024 + (k0+1)*32 + ln]; }
        else if (m == 2) {
            float A0 = g1[s*32+k0]   * rsqrtf(va1[s*32+k0]   + EPSBN);
            float A1 = g1[s*32+k0+1] * rsqrtf(va1[s*32+k0+1] + EPSBN);
            lo = A0 * W2[s*1024 + k0*32 + ln]; hv = A1 * W2[s*1024 + (k0+1)*32 + ln];
        } else {
            float A0 = g2[s*32+k0]   * rsqrtf(va2[s*32+k0]   + EPSBN);
            float A1 = g2[s*32+k0+1] * rsqrtf(va2[s*32+k0+1] + EPSBN);
            lo = A0 * Wsh[k0*32 + ln]; hv = A1 * Wsh[(k0+1)*32 + ln];
        }
        wfrag[i] = pkbf(lo, hv);
    } else {
        for (int i = threadIdx.x; i < 480; i += 256) {
            const int reg = i & 15, hi = (i >> 4) & 1, t = i >> 5;
            const int q = t % 3, s = t / 3;
            const int r = (reg & 3) + 8 * (reg >> 2) + 4 * hi;
            float v;
            if (q == 0) v = b1[s*32 + r];
            else if (q == 1) {
                v = b2[s*32 + r] + bsc[s*32 + r];
                for (int k = 0; k < 32; ++k) {
                    float A = g1[s*32+k] * rsqrtf(va1[s*32+k] + EPSBN);
                    float C = be1[s*32+k] - mu1[s*32+k] * A;
                    v = fmaf(C, W2[s*1024 + k*32 + r], v);
                }
            } else {
                v = bsh[r];
                for (int k = 0; k < 32; ++k) {
                    float A = g2[s*32+k] * rsqrtf(va2[s*32+k] + EPSBN);
                    float C = be2[s*32+k] - mu2[s*32+k] * A;
                    v = fmaf(C, Wsh[k*32 + r], v);
                }
            }
            bconst[i] = v;
        }
    }
}

// relu-only transition: C' acc -> next layer's B-frags (cvt_pk + permlane32).
static __device__ __forceinline__ void reluT(const f32x16& c, bf16x8& f0, bf16x8& f1) {
    unsigned p[8];
    #pragma unroll
    for (int i = 0; i < 8; ++i)
        p[i] = pkbf(fmaxf(c[2 * i], 0.f), fmaxf(c[2 * i + 1], 0.f));
    auto s0 = __builtin_amdgcn_permlane32_swap(p[0], p[2], false, false);
    auto s1 = __builtin_amdgcn_permlane32_swap(p[1], p[3], false, false);
    auto s2 = __builtin_amdgcn_permlane32_swap(p[4], p[6], false, false);
    auto s3 = __builtin_amdgcn_permlane32_swap(p[5], p[7], false, false);
    FU u0, u1;
    u0.u[0] = s0[0]; u0.u[1] = s1[0]; u0.u[2] = s0[1]; u0.u[3] = s1[1];
    u1.u[0] = s2[0]; u1.u[1] = s3[0]; u1.u[2] = s2[1]; u1.u[3] = s3[1];
    f0 = u0.v; f1 = u1.v;
}

struct XR { float4 a, b, c, d; };

static __device__ __forceinline__ XR ldx(const float* __restrict__ X, long ofs, int hi) {
    const float* xb = X + ofs + hi * 8;
    XR r;
    r.a = *(const float4*)(xb);
    r.b = *(const float4*)(xb + 4);
    r.c = *(const float4*)(xb + 16);
    r.d = *(const float4*)(xb + 20);
    return r;
}

static __device__ __forceinline__ void cvtx(const XR& x, bf16x8& b0, bf16x8& b1) {
    FU u0, u1;
    u0.u[0] = pkbf(x.a.x, x.a.y); u0.u[1] = pkbf(x.a.z, x.a.w);
    u0.u[2] = pkbf(x.b.x, x.b.y); u0.u[3] = pkbf(x.b.z, x.b.w);
    u1.u[0] = pkbf(x.c.x, x.c.y); u1.u[1] = pkbf(x.c.z, x.c.w);
    u1.u[2] = pkbf(x.d.x, x.d.y); u1.u[3] = pkbf(x.d.z, x.d.w);
    b0 = u0.v; b1 = u1.v;
}

__global__ __launch_bounds__(256, 3) void k_main(
    const float* __restrict__ X, const int* __restrict__ sid,
    const unsigned* __restrict__ wfrag, const float* __restrict__ bconst,
    float* __restrict__ out, int B, int ntiles) {
    __shared__ unsigned wlds[10240];
    __shared__ float clds[480];
    for (int i = threadIdx.x; i < 10240; i += TPB) wlds[i] = wfrag[i];
    for (int i = threadIdx.x; i < 480; i += TPB) clds[i] = bconst[i];
    __syncthreads();

    const int l  = threadIdx.x & 63;
    const int ln = l & 31;
    const int hi = l >> 5;
    const int wid = (blockIdx.x * TPB + threadIdx.x) >> 6;
    const int nw  = (gridDim.x * TPB) >> 6;

    int t = wid;
    if (t >= ntiles) return;

    // prefetch first tile
    int rc = min(t * 32 + ln, B - 1);
    XR xc = ldx(X, (long)rc * 32, hi);
    int sv = sid[rc];

    for (; t < ntiles; t += nw) {
        bf16x8 bx0, bx1;
        cvtx(xc, bx0, bx1);
        const int svc  = sv;
        const int rowc = t * 32 + ln;

        // prefetch next grid-stride tile
        const int tn = t + nw;
        if (tn < ntiles) {
            int r2 = min(tn * 32 + ln, B - 1);
            xc = ldx(X, (long)r2 * 32, hi);
            sv = sid[r2];
        }

        // opaque LDS bases: defeat LICM (else 160 loop-invariant ds_reads get
        // hoisted into registers and spill)
        int zero = 0;
        asm volatile("" : "+v"(zero));
        const unsigned* wl = wlds + zero;
        const float*    cl = clds + zero;

        float acc[16];
        #pragma unroll
        for (int r = 0; r < 16; ++r) acc[r] = 0.f;

        #pragma unroll
        for (int s = 0; s < 5; ++s) {
            f32x16 a1 = *(const f32x16*)(cl + ((s * 3 + 0) * 2 + hi) * 16);
            f32x16 a2 = *(const f32x16*)(cl + ((s * 3 + 1) * 2 + hi) * 16);
            FU w00, w01, w10, w11, w20, w21, w30, w31;
            w00.q = *(const u32x4*)(wl + (((s * 4 + 0) * 2 + 0) * 64 + l) * 4);
            w01.q = *(const u32x4*)(wl + (((s * 4 + 0) * 2 + 1) * 64 + l) * 4);
            a1 = __builtin_amdgcn_mfma_f32_32x32x16_bf16(w00.v, bx0, a1, 0, 0, 0);
            a1 = __builtin_amdgcn_mfma_f32_32x32x16_bf16(w01.v, bx1, a1, 0, 0, 0);
            w10.q = *(const u32x4*)(wl + (((s * 4 + 1) * 2 + 0) * 64 + l) * 4);
            w11.q = *(const u32x4*)(wl + (((s * 4 + 1) * 2 + 1) * 64 + l) * 4);
            a2 = __builtin_amdgcn_mfma_f32_32x32x16_bf16(w10.v, bx0, a2, 0, 0, 0);
            a2 = __builtin_amdgcn_mfma_f32_32x32x16_bf16(w11.v, bx1, a2, 0, 0, 0);
            bf16x8 h0, h1;
            reluT(a1, h0, h1);
            w20.q = *(const u32x4*)(wl + (((s * 4 + 2) * 2 + 0) * 64 + l) * 4);
            w21.q = *(const u32x4*)(wl + (((s * 4 + 2) * 2 + 1) * 64 + l) * 4);
            a2 = __builtin_amdgcn_mfma_f32_32x32x16_bf16(w20.v, h0, a2, 0, 0, 0);
            a2 = __builtin_amdgcn_mfma_f32_32x32x16_bf16(w21.v, h1, a2, 0, 0, 0);
            bf16x8 g0, g1;
            reluT(a2, g0, g1);
            f32x16 a3 = *(const f32x16*)(cl + ((s * 3 + 2) * 2 + hi) * 16);
            w30.q = *(const u32x4*)(wl + (((s * 4 + 3) * 2 + 0) * 64 + l) * 4);
            w31.q = *(const u32x4*)(wl + (((s * 4 + 3) * 2 + 1) * 64 + l) * 4);
            a3 = __builtin_amdgcn_mfma_f32_32x32x16_bf16(w30.v, g0, a3, 0, 0, 0);
            a3 = __builtin_amdgcn_mfma_f32_32x32x16_bf16(w31.v, g1, a3, 0, 0, 0);

            const bool m = (svc == s);
            #pragma unroll
            for (int r = 0; r < 16; ++r) acc[r] = m ? a3[r] : acc[r];
        }

        if (rowc < B) {
            float* op = out + (long)rowc * 32 + hi * 4;
            #pragma unroll
            for (int q = 0; q < 4; ++q) {
                float4 v;
                v.x = fmaxf(acc[4 * q + 0], 0.f) * 0.92f;
                v.y = fmaxf(acc[4 * q + 1], 0.f) * 0.92f;
                v.z = fmaxf(acc[4 * q + 2], 0.f) * 0.92f;
                v.w = fmaxf(acc[4 * q + 3], 0.f) * 0.92f;
                *(float4*)(op + q * 8) = v;
            }
        }
    }
}

extern "C" void kernel_launch(void* const* d_in, const int* in_sizes, int n_in,
                              void* d_out, int out_size, void* d_ws, size_t ws_size,
                              hipStream_t stream) {
    const float* X   = (const float*)d_in[0];
    const int*   sid = (const int*)d_in[1];
    const float* W1  = (const float*)d_in[2];
    const float* b1  = (const float*)d_in[3];
    const float* g1  = (const float*)d_in[4];
    const float* be1 = (const float*)d_in[5];
    const float* mu1 = (const float*)d_in[6];
    const float* va1 = (const float*)d_in[7];
    const float* W2  = (const float*)d_in[8];
    const float* b2  = (const float*)d_in[9];
    const float* g2  = (const float*)d_in[10];
    const float* be2 = (const float*)d_in[11];
    const float* mu2 = (const float*)d_in[12];
    const float* va2 = (const float*)d_in[13];
    const float* Wsc = (const float*)d_in[14];
    const float* bsc = (const float*)d_in[15];
    const float* Wsh = (const float*)d_in[16];
    const float* bsh = (const float*)d_in[17];
    float* out = (float*)d_out;
    const int B = in_sizes[1];

    unsigned* wfrag = (unsigned*)d_ws;          // 10240 u32
    float* bconst   = (float*)(wfrag + 10240);  // 480 f32

    k_pre<<<41, 256, 0, stream>>>(wfrag, bconst,
                                  W1, b1, g1, be1, mu1, va1,
                                  W2, b2, g2, be2, mu2, va2,
                                  Wsc, bsc, Wsh, bsh);

    const int ntiles = (B + 31) / 32;
    const int nblocks = min(NBLK, (ntiles + 3) / 4);
    k_main<<<nblocks, TPB, 0, stream>>>(X, sid, wfrag, bconst, out, B, ntiles);
}